// Round 9
// baseline (125.025 us; speedup 1.0000x reference)
//
#include <hip/hip_runtime.h>
#include <stdint.h>

typedef __bf16 bf16;
typedef __bf16 bf16x8 __attribute__((ext_vector_type(8)));
typedef __bf16 bf16x4 __attribute__((ext_vector_type(4)));
typedef float f32x4 __attribute__((ext_vector_type(4)));

constexpr int nB = 2, nS = 2048, nD = 768, nH = 12, nDK = 64;
constexpr int nM = nB * nS;  // 4096
constexpr float LN_EPS = 1e-5f;

static __device__ __forceinline__ f32x4 mfma16(bf16x8 a, bf16x8 b, f32x4 c) {
  return __builtin_amdgcn_mfma_f32_16x16x32_bf16(a, b, c, 0, 0, 0);
}

static __device__ __forceinline__ void gll16(const void* g, void* l) {
  __builtin_amdgcn_global_load_lds(
      (const __attribute__((address_space(1))) void*)g,
      (__attribute__((address_space(3))) void*)l, 16, 0, 0);
}

// Stage a 128-row x 64-col bf16 tile (row stride ldk elements) into LDS at dst
// (linear [row][8 chunks of 16B]); global source pre-swizzled: chunk c ^= row&7,
// matching the read-side XOR (involution, rule both-sides-or-neither).
static __device__ __forceinline__ void stage128x64(const bf16* src, int ldk,
                                                   char* dst, int t, int w) {
#pragma unroll
  for (int i = 0; i < 4; ++i) {
    int row = i * 32 + (t >> 3);
    int c = (t & 7) ^ (row & 7);
    gll16(src + (size_t)row * ldk + c * 8, dst + i * 4096 + w * 1024);
  }
}

// ---------------- prep: x -> bf16 ----------------
__global__ __launch_bounds__(256) void k_prep_x(const float* __restrict__ x,
                                                bf16* __restrict__ xb) {
  int i = (blockIdx.x * 256 + threadIdx.x) * 4;
  float4 v = *(const float4*)(x + i);
  bf16x4 o;
  o[0] = (bf16)v.x; o[1] = (bf16)v.y; o[2] = (bf16)v.z; o[3] = (bf16)v.w;
  *(bf16x4*)(xb + i) = o;
}

// ---------------- prep: weights -> bf16, transposed to [n][k] ----------------
__global__ __launch_bounds__(256) void k_prep_w(
    const float* __restrict__ w0, const float* __restrict__ w1,
    const float* __restrict__ w2, const float* __restrict__ w3,
    const float* __restrict__ w4, bf16* __restrict__ wt) {
  __shared__ float tb[64][65];
  int w = blockIdx.z;
  const float* src = (w == 0) ? w0 : (w == 1) ? w1 : (w == 2) ? w2 : (w == 3) ? w3 : w4;
  int k0 = blockIdx.y * 64, n0 = blockIdx.x * 64;
  int tx = threadIdx.x & 63, ty = threadIdx.x >> 6;
#pragma unroll
  for (int it = 0; it < 16; ++it) {
    int r = it * 4 + ty;
    tb[r][tx] = src[(size_t)(k0 + r) * nD + n0 + tx];
  }
  __syncthreads();
  bf16* dst = wt + (size_t)w * nD * nD;
#pragma unroll
  for (int it = 0; it < 16; ++it) {
    int r = it * 4 + ty;
    dst[(size_t)(n0 + r) * nD + k0 + tx] = (bf16)tb[tx][r];
  }
}

// ---------------- QPKV GEMM: C = X @ W (Wt is W^T), 128x128 tile, BK=64 ----------------
// global_load_lds double-buffered staging. K output (widx==2) pre-scaled by
// DK^-0.5*log2(e) so attention scores come out of the MFMA in exp2 domain.
__global__ __launch_bounds__(256) void k_gemm_qpkv(
    const bf16* __restrict__ xb, const bf16* __restrict__ wt,
    bf16* __restrict__ qf, bf16* __restrict__ pf, bf16* __restrict__ kf_,
    bf16* __restrict__ vt) {
  __shared__ alignas(16) char smem[65536];  // [2 bufs][A 16K | B 16K]
  int t = threadIdx.x, lane = t & 63, w = t >> 6;
  int fr = lane & 15, fg = lane >> 4;
  int wm = w >> 1, wn = w & 1;
  int widx = blockIdx.z;
  int m0 = blockIdx.y * 128, n0 = blockIdx.x * 128;
  const bf16* abase = xb + (size_t)m0 * nD;
  const bf16* bbase = wt + (size_t)widx * nD * nD + (size_t)n0 * nD;

  f32x4 acc[4][4];
#pragma unroll
  for (int i = 0; i < 4; ++i)
#pragma unroll
    for (int j = 0; j < 4; ++j) acc[i][j] = (f32x4){0.f, 0.f, 0.f, 0.f};

  stage128x64(abase, nD, smem, t, w);
  stage128x64(bbase, nD, smem + 16384, t, w);
  __syncthreads();
#pragma unroll 1
  for (int kt = 0; kt < 12; ++kt) {
    if (kt < 11) {
      char* nb = smem + ((kt + 1) & 1) * 32768;
      stage128x64(abase + (kt + 1) * 64, nD, nb, t, w);
      stage128x64(bbase + (kt + 1) * 64, nD, nb + 16384, t, w);
    }
    char* Ab = smem + (kt & 1) * 32768;
    char* Bb = Ab + 16384;
#pragma unroll
    for (int ks = 0; ks < 2; ++ks) {
      bf16x8 af[4], bfr[4];
#pragma unroll
      for (int i = 0; i < 4; ++i) {
        int row = wm * 64 + i * 16 + fr;
        af[i] = *(const bf16x8*)(Ab + row * 128 + (((ks * 4 + fg) ^ (row & 7)) << 4));
      }
#pragma unroll
      for (int j = 0; j < 4; ++j) {
        int row = wn * 64 + j * 16 + fr;
        bfr[j] = *(const bf16x8*)(Bb + row * 128 + (((ks * 4 + fg) ^ (row & 7)) << 4));
      }
#pragma unroll
      for (int i = 0; i < 4; ++i)
#pragma unroll
        for (int j = 0; j < 4; ++j) acc[i][j] = mfma16(af[i], bfr[j], acc[i][j]);
    }
    __syncthreads();
  }
  // epilogue
  if (widx < 3) {
    bf16* outf = (widx == 0) ? qf : (widx == 1) ? pf : kf_;
    float oscale = (widx == 2) ? 0.18033688f : 1.0f;  // K: DK^-0.5 * log2(e)
#pragma unroll
    for (int i = 0; i < 4; ++i)
#pragma unroll
      for (int j = 0; j < 4; ++j) {
        int n = n0 + wn * 64 + j * 16 + fr;
#pragma unroll
        for (int r = 0; r < 4; ++r) {
          int m = m0 + wm * 64 + i * 16 + fg * 4 + r;
          outf[(size_t)m * nD + n] = (bf16)(acc[i][j][r] * oscale);
        }
      }
  } else {
#pragma unroll
    for (int i = 0; i < 4; ++i)
#pragma unroll
      for (int j = 0; j < 4; ++j) {
        int n = n0 + wn * 64 + j * 16 + fr;
        int h = n >> 6, dk = n & 63;
        int mbase = m0 + wm * 64 + i * 16 + fg * 4;
        int b = mbase >> 11, s = mbase & (nS - 1);
        int bh = b * nH + h;
        bf16x4 pk;
#pragma unroll
        for (int r = 0; r < 4; ++r) pk[r] = (bf16)acc[i][j][r];
        *(bf16x4*)(vt + ((size_t)bh * nDK + dk) * nS + s) = pk;
      }
  }
}

// ---------------- attention pass 1 + leapfrog -> q_new ----------------
// LDS-traffic-halved structure: wave = 32 q (2 qgroups) x its KEY-HALF (1024
// keys, 32-key tiles). K/V fragment reads are shared across both qgroups ->
// 10 b128 reads per 32qx32k vs 20 per 16qx64k before. 4 waves =
// {qhalf}x{khalf}; key-half partials (unnormalized exp2 softmax adds
// linearly) combined once at the end via LDS exchange; pair members write
// disjoint dv halves. Counted-vmcnt dbuf staging kept. K pre-scaled.
__global__ __launch_bounds__(256) void k_attn(
    const bf16* __restrict__ qf, const bf16* __restrict__ pf,
    const bf16* __restrict__ kf_, const bf16* __restrict__ vt,
    const float* __restrict__ dtp, const float* __restrict__ gatep,
    bf16* __restrict__ qn) {
  // 40KB: stream kh at +kh*16384: [K b0 4K][K b1 4K][V b0 4K][V b1 4K];
  // P: 4 waves x 2KB at +32768. Epilogue exchange overlays [0, 34816).
  __shared__ alignas(16) char lds[40960];
  int t = threadIdx.x, lane = t & 63, w = t >> 6;
  int fr = lane & 15, fg = lane >> 4;
  int qhalf = w & 1, kh = w >> 1, sw = w & 1;
  int blk = blockIdx.x;
  int qt = blk & 31, bh = blk >> 5;
  int b = bh / nH, h = bh % nH;
  int q0 = qt * 64 + qhalf * 32;
  const bf16* Qrow = qf + (size_t)(b * nS) * nD + (size_t)h * nDK;
  const bf16* Prow = pf + (size_t)(b * nS) * nD + (size_t)h * nDK;
  const bf16* Krow = kf_ + (size_t)(b * nS) * nD + (size_t)h * nDK;
  const bf16* Vb = vt + (size_t)bh * nDK * nS;
  const bf16* Kh = Krow + (size_t)(kh * 1024) * nD;  // key-half base (rows)
  const bf16* Vh = Vb + kh * 1024;                   // key-half base (cols)
  char* sb = lds + kh * 16384;
  char* myp = lds + 32768 + w * 2048;

  // Q fragments (B operand): col = q, k-chunk fg*8 (+32 for slice 1)
  bf16x8 qa[2][2];
#pragma unroll
  for (int qg = 0; qg < 2; ++qg)
#pragma unroll
    for (int ks = 0; ks < 2; ++ks)
      qa[qg][ks] =
          *(const bf16x8*)(Qrow + (size_t)(q0 + qg * 16 + fr) * nD + ks * 32 + fg * 8);

  f32x4 o[2][4];  // o[qg][df]: O^T[dv=df*16+fg*4+r][q=qg*16+fr] (key-half partial)
#pragma unroll
  for (int qg = 0; qg < 2; ++qg)
#pragma unroll
    for (int df = 0; df < 4; ++df) o[qg][df] = (f32x4){0.f, 0.f, 0.f, 0.f};
  float lr0 = 0.f, lr1 = 0.f;  // lane-partial row sums per qgroup

  // STAGE one 32-key tile of this wave's stream: K [32 keys][128B] (chunk
  // swizzle c^(row&7)) and V^T [64 dv][64B] (chunk swizzle c^((row>>1)&3)),
  // pre-swizzled on the global source; LDS dest linear (wave-uniform+lane*16).
#define STAGE(bufsel, kt)                                                      \
  {                                                                            \
    _Pragma("unroll") for (int i = 0; i < 2; ++i) {                            \
      int slot = sw * 128 + i * 64 + lane;                                     \
      int kr = slot >> 3, kc = slot & 7;                                       \
      gll16(Kh + (size_t)((kt)*32 + kr) * nD + (kc ^ (kr & 7)) * 8,            \
            sb + (bufsel)*4096 + sw * 2048 + i * 1024);                        \
      int vr = slot >> 2, vc = slot & 3;                                       \
      gll16(Vh + (size_t)vr * nS + (kt)*32 + (vc ^ ((vr >> 1) & 3)) * 8,       \
            sb + 8192 + (bufsel)*4096 + sw * 2048 + i * 1024);                 \
    }                                                                          \
  }

#define COMPUTE(bufsel)                                                        \
  {                                                                            \
    char* bK = sb + (bufsel)*4096;                                             \
    char* bV = sb + 8192 + (bufsel)*4096;                                      \
    f32x4 sf[2][2];                                                            \
    _Pragma("unroll") for (int kfi = 0; kfi < 2; ++kfi) {                      \
      int key = kfi * 16 + fr;                                                 \
      bf16x8 ka = *(const bf16x8*)(bK + key * 128 + ((fg ^ (key & 7)) << 4));  \
      bf16x8 kc2 =                                                             \
          *(const bf16x8*)(bK + key * 128 + (((4 + fg) ^ (key & 7)) << 4));    \
      _Pragma("unroll") for (int qg = 0; qg < 2; ++qg) {                       \
        f32x4 s = mfma16(ka, qa[qg][0], (f32x4){0.f, 0.f, 0.f, 0.f});          \
        sf[qg][kfi] = mfma16(kc2, qa[qg][1], s);                               \
      }                                                                        \
    }                                                                          \
    _Pragma("unroll") for (int qg = 0; qg < 2; ++qg) {                         \
      float ts = 0.f;                                                          \
      _Pragma("unroll") for (int kfi = 0; kfi < 2; ++kfi) {                    \
        bf16x4 pk;                                                             \
        _Pragma("unroll") for (int r = 0; r < 4; ++r) {                        \
          float e = __builtin_exp2f(sf[qg][kfi][r]);                           \
          ts += e;                                                             \
          pk[r] = (bf16)e;                                                     \
        }                                                                      \
        int cp = (kfi * 2 + (fg >> 1)) ^ ((fr >> 1) & 3);                      \
        *(bf16x4*)(myp + qg * 1024 + fr * 64 + cp * 16 + (fg & 1) * 8) = pk;   \
      }                                                                        \
      if (qg == 0) lr0 += ts; else lr1 += ts;                                  \
    }                                                                          \
    bf16x8 vv[4];                                                              \
    _Pragma("unroll") for (int df = 0; df < 4; ++df) {                         \
      int row = df * 16 + fr;                                                  \
      vv[df] =                                                                 \
          *(const bf16x8*)(bV + row * 64 + ((fg ^ ((row >> 1) & 3)) << 4));    \
    }                                                                          \
    _Pragma("unroll") for (int qg = 0; qg < 2; ++qg) {                         \
      bf16x8 pb = *(const bf16x8*)(myp + qg * 1024 + fr * 64 +                 \
                                   ((fg ^ ((fr >> 1) & 3)) << 4));             \
      _Pragma("unroll") for (int df = 0; df < 4; ++df)                         \
          o[qg][df] = mfma16(vv[df], pb, o[qg][df]);                           \
    }                                                                          \
  }

#define VMCNT4 asm volatile("s_waitcnt vmcnt(4)" ::: "memory")
#define VMCNT0 asm volatile("s_waitcnt vmcnt(0)" ::: "memory")
#define BAR __builtin_amdgcn_s_barrier()

  STAGE(0, 0);
#pragma unroll 1
  for (int kt = 0; kt < 32; kt += 2) {
    STAGE(1, kt + 1);  // prefetch stays in flight across barrier
    VMCNT4;            // wait current buf's 4 loads only
    BAR;
    COMPUTE(0);
    BAR;
    if (kt + 2 < 32) {
      STAGE(0, kt + 2);
      VMCNT4;
    } else {
      VMCNT0;
    }
    BAR;
    COMPUTE(1);
    BAR;
  }
#undef STAGE
#undef COMPUTE
#undef VMCNT4
#undef VMCNT0
#undef BAR

  // finish lane-partial l within this key-half (4 lanes share each q-row)
  lr0 += __shfl_xor(lr0, 16);
  lr0 += __shfl_xor(lr0, 32);
  lr1 += __shfl_xor(lr1, 16);
  lr1 += __shfl_xor(lr1, 32);

  // exchange key-half partials with partner wave (w^2), overlaying dead LDS.
  // Last loop barrier guarantees all tile reads are done.
  char* ex = lds + w * 8704;
#pragma unroll
  for (int qg = 0; qg < 2; ++qg)
#pragma unroll
    for (int df = 0; df < 4; ++df)
      *(f32x4*)(ex + (qg * 4 + df) * 1024 + lane * 16) = o[qg][df];
  *(float*)(ex + 8192 + lane * 8) = lr0;
  *(float*)(ex + 8192 + lane * 8 + 4) = lr1;
  __syncthreads();
  const char* px = lds + (w ^ 2) * 8704;

  // leapfrog: q_new = q + dt*p - (dt^2/2)*gate*pe1 ; this wave writes its
  // dv-half (kh -> df = kh*2 + {0,1}), pair covers all 64 dv.
  float dt = dtp[0], gate = gatep[0];
  float c2 = 0.5f * dt * dt * gate;
#pragma unroll
  for (int qg = 0; qg < 2; ++qg) {
    float plr = *(const float*)(px + 8192 + lane * 8 + qg * 4);
    float inv = 1.f / ((qg == 0 ? lr0 : lr1) + plr);
    int q = q0 + qg * 16 + fr;
#pragma unroll
    for (int dfi = 0; dfi < 2; ++dfi) {
      int df = kh * 2 + dfi;
      f32x4 po = *(const f32x4*)(px + (qg * 4 + df) * 1024 + lane * 16);
      int dk = df * 16 + fg * 4;
      bf16x4 qv4 = *(const bf16x4*)(Qrow + (size_t)q * nD + dk);
      bf16x4 pv4 = *(const bf16x4*)(Prow + (size_t)q * nD + dk);
      bf16x4 ov;
#pragma unroll
      for (int r = 0; r < 4; ++r) {
        float pe = (o[qg][df][r] + po[r]) * inv;
        ov[r] = (bf16)((float)qv4[r] + dt * (float)pv4[r] - c2 * pe);
      }
      *(bf16x4*)(qn + ((size_t)(b * nS) + q) * nD + h * nDK + dk) = ov;
    }
  }
}

// ---------------- output GEMM: outp = qn @ Wo + bo + x (f32) ----------------
__global__ __launch_bounds__(256) void k_gemm_out(
    const bf16* __restrict__ qn, const bf16* __restrict__ wto,
    const float* __restrict__ bo, const float* __restrict__ x,
    float* __restrict__ outp) {
  __shared__ alignas(16) char smem[65536];
  int t = threadIdx.x, lane = t & 63, w = t >> 6;
  int fr = lane & 15, fg = lane >> 4;
  int wm = w >> 1, wn = w & 1;
  int m0 = blockIdx.y * 128, n0 = blockIdx.x * 128;
  const bf16* abase = qn + (size_t)m0 * nD;
  const bf16* bbase = wto + (size_t)n0 * nD;

  f32x4 acc[4][4];
#pragma unroll
  for (int i = 0; i < 4; ++i)
#pragma unroll
    for (int j = 0; j < 4; ++j) acc[i][j] = (f32x4){0.f, 0.f, 0.f, 0.f};

  stage128x64(abase, nD, smem, t, w);
  stage128x64(bbase, nD, smem + 16384, t, w);
  __syncthreads();
#pragma unroll 1
  for (int kt = 0; kt < 12; ++kt) {
    if (kt < 11) {
      char* nb = smem + ((kt + 1) & 1) * 32768;
      stage128x64(abase + (kt + 1) * 64, nD, nb, t, w);
      stage128x64(bbase + (kt + 1) * 64, nD, nb + 16384, t, w);
    }
    char* Ab = smem + (kt & 1) * 32768;
    char* Bb = Ab + 16384;
#pragma unroll
    for (int ks = 0; ks < 2; ++ks) {
      bf16x8 af[4], bfr[4];
#pragma unroll
      for (int i = 0; i < 4; ++i) {
        int row = wm * 64 + i * 16 + fr;
        af[i] = *(const bf16x8*)(Ab + row * 128 + (((ks * 4 + fg) ^ (row & 7)) << 4));
      }
#pragma unroll
      for (int j = 0; j < 4; ++j) {
        int row = wn * 64 + j * 16 + fr;
        bfr[j] = *(const bf16x8*)(Bb + row * 128 + (((ks * 4 + fg) ^ (row & 7)) << 4));
      }
#pragma unroll
      for (int i = 0; i < 4; ++i)
#pragma unroll
        for (int j = 0; j < 4; ++j) acc[i][j] = mfma16(af[i], bfr[j], acc[i][j]);
    }
    __syncthreads();
  }
#pragma unroll
  for (int i = 0; i < 4; ++i)
#pragma unroll
    for (int j = 0; j < 4; ++j) {
      int n = n0 + wn * 64 + j * 16 + fr;
      float bias = bo[n];
#pragma unroll
      for (int r = 0; r < 4; ++r) {
        int m = m0 + wm * 64 + i * 16 + fg * 4 + r;
        outp[(size_t)m * nD + n] = acc[i][j][r] + bias + x[(size_t)m * nD + n];
      }
    }
}

// ---------------- LayerNorm (in-place on d_out), one wave per row ----------------
__global__ __launch_bounds__(256) void k_ln(const float* outp,
                                            const float* __restrict__ gamma,
                                            const float* __restrict__ beta,
                                            float* y) {
  int t = threadIdx.x, lane = t & 63, w = t >> 6;
  int row = blockIdx.x * 4 + w;
  const float* rp = outp + (size_t)row * nD;
  float v[12], s1 = 0.f, s2 = 0.f;
#pragma unroll
  for (int i = 0; i < 12; ++i) {
    v[i] = rp[lane + i * 64];
    s1 += v[i];
    s2 += v[i] * v[i];
  }
#pragma unroll
  for (int d = 1; d < 64; d <<= 1) {
    s1 += __shfl_xor(s1, d);
    s2 += __shfl_xor(s2, d);
  }
  float mu = s1 * (1.f / 768.f);
  float var = s2 * (1.f / 768.f) - mu * mu;
  float rstd = rsqrtf(var + LN_EPS);
  float* yp = y + (size_t)row * nD;
#pragma unroll
  for (int i = 0; i < 12; ++i) {
    int n = lane + i * 64;
    yp[n] = (v[i] - mu) * rstd * gamma[n] + beta[n];
  }
}

extern "C" void kernel_launch(void* const* d_in, const int* in_sizes, int n_in,
                              void* d_out, int out_size, void* d_ws, size_t ws_size,
                              hipStream_t stream) {
  const float* x = (const float*)d_in[0];
  const float* Wq = (const float*)d_in[1];
  const float* Wp = (const float*)d_in[2];
  const float* Wk = (const float*)d_in[3];
  const float* Wv = (const float*)d_in[4];
  const float* Wo = (const float*)d_in[5];
  const float* bo = (const float*)d_in[6];
  const float* gamma = (const float*)d_in[7];
  const float* beta = (const float*)d_in[8];
  const float* dt = (const float*)d_in[9];
  const float* gate = (const float*)d_in[10];

  char* ws = (char*)d_ws;
  const size_t szb = (size_t)nM * nD * 2;  // 6,291,456 bytes per bf16 [4096][768]
  bf16* xb = (bf16*)(ws + 0 * szb);        // reused as qn after QPKV GEMM
  bf16* qf = (bf16*)(ws + 1 * szb);
  bf16* pf = (bf16*)(ws + 2 * szb);
  bf16* kf_ = (bf16*)(ws + 3 * szb);
  bf16* vt = (bf16*)(ws + 4 * szb);
  bf16* wt = (bf16*)(ws + 5 * szb);  // 5 * 768*768 bf16 = 5,898,240 bytes
  bf16* qn = xb;
  float* outp = (float*)d_out;  // out-GEMM result, LN runs in place

  k_prep_x<<<dim3(nM * nD / 1024), dim3(256), 0, stream>>>(x, xb);
  k_prep_w<<<dim3(12, 12, 5), dim3(256), 0, stream>>>(Wq, Wp, Wk, Wv, Wo, wt);
  k_gemm_qpkv<<<dim3(6, 32, 4), dim3(256), 0, stream>>>(xb, wt, qf, pf, kf_, vt);
  k_attn<<<dim3(768), dim3(256), 0, stream>>>(qf, pf, kf_, vt, dt, gate, qn);
  k_gemm_out<<<dim3(6, 32), dim3(256), 0, stream>>>(qn, wt + 4 * (size_t)nD * nD, bo, x, outp);
  k_ln<<<dim3(nM / 4), dim3(256), 0, stream>>>(outp, gamma, beta, (float*)d_out);
}

// Round 10
// 115.307 us; speedup vs baseline: 1.0843x; 1.0843x over previous
//
#include <hip/hip_runtime.h>
#include <stdint.h>

typedef __bf16 bf16;
typedef __bf16 bf16x8 __attribute__((ext_vector_type(8)));
typedef __bf16 bf16x4 __attribute__((ext_vector_type(4)));
typedef float f32x4 __attribute__((ext_vector_type(4)));

constexpr int nB = 2, nS = 2048, nD = 768, nH = 12, nDK = 64;
constexpr int nM = nB * nS;  // 4096
constexpr float LN_EPS = 1e-5f;

static __device__ __forceinline__ f32x4 mfma16(bf16x8 a, bf16x8 b, f32x4 c) {
  return __builtin_amdgcn_mfma_f32_16x16x32_bf16(a, b, c, 0, 0, 0);
}

static __device__ __forceinline__ void gll16(const void* g, void* l) {
  __builtin_amdgcn_global_load_lds(
      (const __attribute__((address_space(1))) void*)g,
      (__attribute__((address_space(3))) void*)l, 16, 0, 0);
}

// ---------------- prep: x -> bf16 ----------------
__global__ __launch_bounds__(256) void k_prep_x(const float* __restrict__ x,
                                                bf16* __restrict__ xb) {
  int i = (blockIdx.x * 256 + threadIdx.x) * 4;
  float4 v = *(const float4*)(x + i);
  bf16x4 o;
  o[0] = (bf16)v.x; o[1] = (bf16)v.y; o[2] = (bf16)v.z; o[3] = (bf16)v.w;
  *(bf16x4*)(xb + i) = o;
}

// ---------------- prep: weights -> bf16, transposed to [n][k] ----------------
__global__ __launch_bounds__(256) void k_prep_w(
    const float* __restrict__ w0, const float* __restrict__ w1,
    const float* __restrict__ w2, const float* __restrict__ w3,
    const float* __restrict__ w4, bf16* __restrict__ wt) {
  __shared__ float tb[64][65];
  int w = blockIdx.z;
  const float* src = (w == 0) ? w0 : (w == 1) ? w1 : (w == 2) ? w2 : (w == 3) ? w3 : w4;
  int k0 = blockIdx.y * 64, n0 = blockIdx.x * 64;
  int tx = threadIdx.x & 63, ty = threadIdx.x >> 6;
#pragma unroll
  for (int it = 0; it < 16; ++it) {
    int r = it * 4 + ty;
    tb[r][tx] = src[(size_t)(k0 + r) * nD + n0 + tx];
  }
  __syncthreads();
  bf16* dst = wt + (size_t)w * nD * nD;
#pragma unroll
  for (int it = 0; it < 16; ++it) {
    int r = it * 4 + ty;
    dst[(size_t)(n0 + r) * nD + k0 + tx] = (bf16)tb[tx][r];
  }
}

// ---------------- QPKV GEMM: C = X @ W (Wt is W^T), 128x128 tile, BK=64 ----------------
// All LDS read offsets and staging sources hoisted to registers pre-loop;
// double-buffer bases are compile-time immediates. K output (widx==2)
// pre-scaled by DK^-0.5*log2(e).
__global__ __launch_bounds__(256, 2) void k_gemm_qpkv(
    const bf16* __restrict__ xb, const bf16* __restrict__ wt,
    bf16* __restrict__ qf, bf16* __restrict__ pf, bf16* __restrict__ kf_,
    bf16* __restrict__ vt) {
  __shared__ alignas(16) char smem[65536];  // [2 bufs][A 16K | B 16K]
  int t = threadIdx.x, lane = t & 63, w = t >> 6;
  int fr = lane & 15, fg = lane >> 4;
  int wm = w >> 1, wn = w & 1;
  int widx = blockIdx.z;
  int m0 = blockIdx.y * 128, n0 = blockIdx.x * 128;
  const bf16* abase = xb + (size_t)m0 * nD;
  const bf16* bbase = wt + (size_t)widx * nD * nD + (size_t)n0 * nD;

  f32x4 acc[4][4];
#pragma unroll
  for (int i = 0; i < 4; ++i)
#pragma unroll
    for (int j = 0; j < 4; ++j) acc[i][j] = (f32x4){0.f, 0.f, 0.f, 0.f};

  // hoisted LDS read offsets (loop-invariant)
  int aoff[2][4], boff[2][4];
#pragma unroll
  for (int ks = 0; ks < 2; ++ks) {
#pragma unroll
    for (int i = 0; i < 4; ++i) {
      int row = wm * 64 + i * 16 + fr;
      aoff[ks][i] = row * 128 + (((ks * 4 + fg) ^ (row & 7)) << 4);
      int rowb = wn * 64 + i * 16 + fr;
      boff[ks][i] = 16384 + rowb * 128 + (((ks * 4 + fg) ^ (rowb & 7)) << 4);
    }
  }
  // hoisted staging sources (pre-swizzled chunk, involution with read XOR)
  const bf16 *asrc[4], *bsrc[4];
#pragma unroll
  for (int i = 0; i < 4; ++i) {
    int row = i * 32 + (t >> 3);
    int c = (t & 7) ^ (row & 7);
    asrc[i] = abase + (size_t)row * nD + c * 8;
    bsrc[i] = bbase + (size_t)row * nD + c * 8;
  }

#define STAGEG(BUF, kt)                                                        \
  {                                                                            \
    _Pragma("unroll") for (int i = 0; i < 4; ++i) {                            \
      gll16(asrc[i] + (kt)*64, smem + (BUF) + i * 4096 + w * 1024);            \
      gll16(bsrc[i] + (kt)*64, smem + (BUF) + 16384 + i * 4096 + w * 1024);    \
    }                                                                          \
  }

#define COMPUTEG(BUF)                                                          \
  {                                                                            \
    _Pragma("unroll") for (int ks = 0; ks < 2; ++ks) {                         \
      bf16x8 af[4], bfr[4];                                                    \
      _Pragma("unroll") for (int i = 0; i < 4; ++i)                            \
          af[i] = *(const bf16x8*)(smem + (BUF) + aoff[ks][i]);                \
      _Pragma("unroll") for (int j = 0; j < 4; ++j)                            \
          bfr[j] = *(const bf16x8*)(smem + (BUF) + boff[ks][j]);               \
      _Pragma("unroll") for (int i = 0; i < 4; ++i)                            \
          _Pragma("unroll") for (int j = 0; j < 4; ++j) acc[i][j] =            \
          mfma16(af[i], bfr[j], acc[i][j]);                                    \
    }                                                                          \
  }

  STAGEG(0, 0);
  __syncthreads();
#pragma unroll 1
  for (int kt = 0; kt < 12; kt += 2) {
    if (kt + 1 < 12) STAGEG(32768, kt + 1);
    COMPUTEG(0);
    __syncthreads();
    if (kt + 2 < 12) STAGEG(0, kt + 2);
    COMPUTEG(32768);
    __syncthreads();
  }
#undef STAGEG
#undef COMPUTEG

  // epilogue
  if (widx < 3) {
    bf16* outf = (widx == 0) ? qf : (widx == 1) ? pf : kf_;
    float oscale = (widx == 2) ? 0.18033688f : 1.0f;  // K: DK^-0.5 * log2(e)
#pragma unroll
    for (int i = 0; i < 4; ++i)
#pragma unroll
      for (int j = 0; j < 4; ++j) {
        int n = n0 + wn * 64 + j * 16 + fr;
#pragma unroll
        for (int r = 0; r < 4; ++r) {
          int m = m0 + wm * 64 + i * 16 + fg * 4 + r;
          outf[(size_t)m * nD + n] = (bf16)(acc[i][j][r] * oscale);
        }
      }
  } else {
#pragma unroll
    for (int i = 0; i < 4; ++i)
#pragma unroll
      for (int j = 0; j < 4; ++j) {
        int n = n0 + wn * 64 + j * 16 + fr;
        int h = n >> 6, dk = n & 63;
        int mbase = m0 + wm * 64 + i * 16 + fg * 4;
        int b = mbase >> 11, s = mbase & (nS - 1);
        int bh = b * nH + h;
        bf16x4 pk;
#pragma unroll
        for (int r = 0; r < 4; ++r) pk[r] = (bf16)acc[i][j][r];
        *(bf16x4*)(vt + ((size_t)bh * nDK + dk) * nS + s) = pk;
      }
  }
}

// ---------------- attention pass 1 + leapfrog -> q_new ----------------
// R8 structure (swapped QK^T, K/V LDS dbuf, counted vmcnt, unnormalized exp2
// softmax with in-register all-ones MFMA row-sum) with ALL LDS addressing
// hoisted: per-lane byte offsets computed once, dbuf bases as compile-time
// immediates -> in-loop VALU is just exp2 + cvt. launch_bounds(256,3) gives
// the register budget (grid fixes occupancy at 3 blocks/CU anyway).
__global__ __launch_bounds__(256, 3) void k_attn(
    const bf16* __restrict__ qf, const bf16* __restrict__ pf,
    const bf16* __restrict__ kf_, const bf16* __restrict__ vt,
    const float* __restrict__ dtp, const float* __restrict__ gatep,
    bf16* __restrict__ qn) {
  // LDS: K dbuf @0/@8192 | V dbuf @16384/@24576 | P 4x2KB @32768  = 40KB
  __shared__ alignas(16) char lds[40960];
  int t = threadIdx.x, lane = t & 63, w = t >> 6;
  int fr = lane & 15, fg = lane >> 4;
  int blk = blockIdx.x;
  int qt = blk & 31, bh = blk >> 5;
  int b = bh / nH, h = bh % nH;
  int q0 = qt * 64 + w * 16;
  const bf16* Qrow = qf + (size_t)(b * nS) * nD + (size_t)h * nDK;
  const bf16* Prow = pf + (size_t)(b * nS) * nD + (size_t)h * nDK;
  const bf16* Krow = kf_ + (size_t)(b * nS) * nD + (size_t)h * nDK;
  const bf16* Vb = vt + (size_t)bh * nDK * nS;
  char* myp = lds + 32768 + w * 2048;

  bf16x8 qa[2];
#pragma unroll
  for (int ks = 0; ks < 2; ++ks)
    qa[ks] = *(const bf16x8*)(Qrow + (size_t)(q0 + fr) * nD + ks * 32 + fg * 8);

  // all-ones A-fragment: MFMA row-sum accumulator operand (no LDS needed)
  bf16x8 vone;
#pragma unroll
  for (int i = 0; i < 8; ++i) vone[i] = (bf16)1.0f;

  f32x4 o[5];  // o[0..3]: O^T[dv=df*16+fg*4+r][q=fr]; o[4]: row-sum lr
#pragma unroll
  for (int df = 0; df < 5; ++df) o[df] = (f32x4){0.f, 0.f, 0.f, 0.f};

  // ---- hoisted LDS read/write offsets (bytes, loop-invariant) ----
  int koA[4], koB[4];
#pragma unroll
  for (int kfi = 0; kfi < 4; ++kfi) {
    int key = kfi * 16 + fr;
    koA[kfi] = key * 128 + ((fg ^ (key & 7)) << 4);
    koB[kfi] = key * 128 + (((4 + fg) ^ (key & 7)) << 4);
  }
  int vo[2][4], pr[2], pw[4];
#pragma unroll
  for (int ks = 0; ks < 2; ++ks) {
    pr[ks] = fr * 128 + (((ks * 4 + fg) ^ (fr & 7)) << 4);
#pragma unroll
    for (int df = 0; df < 4; ++df) {
      int row = df * 16 + fr;
      vo[ks][df] = row * 128 + (((ks * 4 + fg) ^ (row & 7)) << 4);
    }
  }
#pragma unroll
  for (int kfi = 0; kfi < 4; ++kfi) {
    int blk16 = kfi * 2 + (fg >> 1);
    pw[kfi] = fr * 128 + (((blk16 ^ (fr & 7)) << 4) | ((fg & 1) << 3));
  }

  // ---- hoisted staging sources (pre-swizzled; involution with read XOR) ----
  const bf16 *ks0, *ks1, *vs0, *vs1;
  {
    int r0 = w * 16 + (lane >> 3), c0 = (lane & 7) ^ (r0 & 7);
    int r1 = r0 + 8, c1 = (lane & 7) ^ (r1 & 7);
    ks0 = Krow + (size_t)r0 * nD + c0 * 8;
    ks1 = Krow + (size_t)r1 * nD + c1 * 8;
    vs0 = Vb + (size_t)r0 * nS + c0 * 8;
    vs1 = Vb + (size_t)r1 * nS + c1 * 8;
  }

#define STAGE(KB, VB, kt)                                                      \
  {                                                                            \
    gll16(ks0 + (size_t)(kt)*64 * nD, lds + (KB) + w * 2048);                  \
    gll16(vs0 + (kt)*64, lds + (VB) + w * 2048);                               \
    gll16(ks1 + (size_t)(kt)*64 * nD, lds + (KB) + w * 2048 + 1024);           \
    gll16(vs1 + (kt)*64, lds + (VB) + w * 2048 + 1024);                        \
  }

#define COMPUTE(KB, VB)                                                        \
  {                                                                            \
    f32x4 sf[4];                                                               \
    _Pragma("unroll") for (int kfi = 0; kfi < 4; ++kfi) {                      \
      bf16x8 ka = *(const bf16x8*)(lds + (KB) + koA[kfi]);                     \
      bf16x8 kc = *(const bf16x8*)(lds + (KB) + koB[kfi]);                     \
      f32x4 s = mfma16(ka, qa[0], (f32x4){0.f, 0.f, 0.f, 0.f});                \
      sf[kfi] = mfma16(kc, qa[1], s);                                          \
    }                                                                          \
    _Pragma("unroll") for (int kfi = 0; kfi < 4; ++kfi) {                      \
      bf16x4 pk;                                                               \
      _Pragma("unroll") for (int r = 0; r < 4; ++r)                            \
          pk[r] = (bf16)__builtin_exp2f(sf[kfi][r]);                           \
      *(bf16x4*)(myp + pw[kfi]) = pk;                                          \
    }                                                                          \
    _Pragma("unroll") for (int ks = 0; ks < 2; ++ks) {                         \
      bf16x8 pb = *(const bf16x8*)(myp + pr[ks]);                              \
      _Pragma("unroll") for (int df = 0; df < 4; ++df) {                       \
        bf16x8 vv = *(const bf16x8*)(lds + (VB) + vo[ks][df]);                 \
        o[df] = mfma16(vv, pb, o[df]);                                         \
      }                                                                        \
      o[4] = mfma16(vone, pb, o[4]);                                           \
    }                                                                          \
  }

#define VMCNT4 asm volatile("s_waitcnt vmcnt(4)" ::: "memory")
#define VMCNT0 asm volatile("s_waitcnt vmcnt(0)" ::: "memory")
#define BAR __builtin_amdgcn_s_barrier()

  STAGE(0, 16384, 0);
#pragma unroll 1
  for (int kt = 0; kt < 32; kt += 2) {
    STAGE(8192, 24576, kt + 1);  // prefetch stays in flight across barrier
    VMCNT4;                      // wait current buf's 4 loads only
    BAR;
    COMPUTE(0, 16384);
    BAR;
    if (kt + 2 < 32) {
      STAGE(0, 16384, kt + 2);
      VMCNT4;
    } else {
      VMCNT0;
    }
    BAR;
    COMPUTE(8192, 24576);
    BAR;
  }
#undef STAGE
#undef COMPUTE
#undef VMCNT4
#undef VMCNT0
#undef BAR

  // leapfrog: q_new = q + dt*p - (dt^2/2)*gate*pe1
  float dt = dtp[0], gate = gatep[0];
  float c2 = 0.5f * dt * dt * gate;
  float inv = 1.f / o[4][0];  // lr, identical in every lane sharing this q
  int qrow = q0 + fr;
#pragma unroll
  for (int df = 0; df < 4; ++df) {
    int dk = df * 16 + fg * 4;
    bf16x4 qv4 = *(const bf16x4*)(Qrow + (size_t)qrow * nD + dk);
    bf16x4 pv4 = *(const bf16x4*)(Prow + (size_t)qrow * nD + dk);
    bf16x4 ov;
#pragma unroll
    for (int r = 0; r < 4; ++r) {
      float pe = o[df][r] * inv;
      ov[r] = (bf16)((float)qv4[r] + dt * (float)pv4[r] - c2 * pe);
    }
    *(bf16x4*)(qn + ((size_t)(b * nS) + qrow) * nD + h * nDK + dk) = ov;
  }
}

// ---------------- output GEMM: outp = qn @ Wo + bo + x (f32) ----------------
__global__ __launch_bounds__(256, 2) void k_gemm_out(
    const bf16* __restrict__ qn, const bf16* __restrict__ wto,
    const float* __restrict__ bo, const float* __restrict__ x,
    float* __restrict__ outp) {
  __shared__ alignas(16) char smem[65536];
  int t = threadIdx.x, lane = t & 63, w = t >> 6;
  int fr = lane & 15, fg = lane >> 4;
  int wm = w >> 1, wn = w & 1;
  int m0 = blockIdx.y * 128, n0 = blockIdx.x * 128;
  const bf16* abase = qn + (size_t)m0 * nD;
  const bf16* bbase = wto + (size_t)n0 * nD;

  f32x4 acc[4][4];
#pragma unroll
  for (int i = 0; i < 4; ++i)
#pragma unroll
    for (int j = 0; j < 4; ++j) acc[i][j] = (f32x4){0.f, 0.f, 0.f, 0.f};

  int aoff[2][4], boff[2][4];
#pragma unroll
  for (int ks = 0; ks < 2; ++ks) {
#pragma unroll
    for (int i = 0; i < 4; ++i) {
      int row = wm * 64 + i * 16 + fr;
      aoff[ks][i] = row * 128 + (((ks * 4 + fg) ^ (row & 7)) << 4);
      int rowb = wn * 64 + i * 16 + fr;
      boff[ks][i] = 16384 + rowb * 128 + (((ks * 4 + fg) ^ (rowb & 7)) << 4);
    }
  }
  const bf16 *asrc[4], *bsrc[4];
#pragma unroll
  for (int i = 0; i < 4; ++i) {
    int row = i * 32 + (t >> 3);
    int c = (t & 7) ^ (row & 7);
    asrc[i] = abase + (size_t)row * nD + c * 8;
    bsrc[i] = bbase + (size_t)row * nD + c * 8;
  }

#define STAGEG(BUF, kt)                                                        \
  {                                                                            \
    _Pragma("unroll") for (int i = 0; i < 4; ++i) {                            \
      gll16(asrc[i] + (kt)*64, smem + (BUF) + i * 4096 + w * 1024);            \
      gll16(bsrc[i] + (kt)*64, smem + (BUF) + 16384 + i * 4096 + w * 1024);    \
    }                                                                          \
  }

#define COMPUTEG(BUF)                                                          \
  {                                                                            \
    _Pragma("unroll") for (int ks = 0; ks < 2; ++ks) {                         \
      bf16x8 af[4], bfr[4];                                                    \
      _Pragma("unroll") for (int i = 0; i < 4; ++i)                            \
          af[i] = *(const bf16x8*)(smem + (BUF) + aoff[ks][i]);                \
      _Pragma("unroll") for (int j = 0; j < 4; ++j)                            \
          bfr[j] = *(const bf16x8*)(smem + (BUF) + boff[ks][j]);               \
      _Pragma("unroll") for (int i = 0; i < 4; ++i)                            \
          _Pragma("unroll") for (int j = 0; j < 4; ++j) acc[i][j] =            \
          mfma16(af[i], bfr[j], acc[i][j]);                                    \
    }                                                                          \
  }

  STAGEG(0, 0);
  __syncthreads();
#pragma unroll 1
  for (int kt = 0; kt < 12; kt += 2) {
    if (kt + 1 < 12) STAGEG(32768, kt + 1);
    COMPUTEG(0);
    __syncthreads();
    if (kt + 2 < 12) STAGEG(0, kt + 2);
    COMPUTEG(32768);
    __syncthreads();
  }
#undef STAGEG
#undef COMPUTEG

#pragma unroll
  for (int i = 0; i < 4; ++i)
#pragma unroll
    for (int j = 0; j < 4; ++j) {
      int n = n0 + wn * 64 + j * 16 + fr;
      float bias = bo[n];
#pragma unroll
      for (int r = 0; r < 4; ++r) {
        int m = m0 + wm * 64 + i * 16 + fg * 4 + r;
        outp[(size_t)m * nD + n] = acc[i][j][r] + bias + x[(size_t)m * nD + n];
      }
    }
}

// ---------------- LayerNorm (in-place on d_out), one wave per row ----------------
__global__ __launch_bounds__(256) void k_ln(const float* outp,
                                            const float* __restrict__ gamma,
                                            const float* __restrict__ beta,
                                            float* y) {
  int t = threadIdx.x, lane = t & 63, w = t >> 6;
  int row = blockIdx.x * 4 + w;
  const float* rp = outp + (size_t)row * nD;
  float v[12], s1 = 0.f, s2 = 0.f;
#pragma unroll
  for (int i = 0; i < 12; ++i) {
    v[i] = rp[lane + i * 64];
    s1 += v[i];
    s2 += v[i] * v[i];
  }
#pragma unroll
  for (int d = 1; d < 64; d <<= 1) {
    s1 += __shfl_xor(s1, d);
    s2 += __shfl_xor(s2, d);
  }
  float mu = s1 * (1.f / 768.f);
  float var = s2 * (1.f / 768.f) - mu * mu;
  float rstd = rsqrtf(var + LN_EPS);
  float* yp = y + (size_t)row * nD;
#pragma unroll
  for (int i = 0; i < 12; ++i) {
    int n = lane + i * 64;
    yp[n] = (v[i] - mu) * rstd * gamma[n] + beta[n];
  }
}

extern "C" void kernel_launch(void* const* d_in, const int* in_sizes, int n_in,
                              void* d_out, int out_size, void* d_ws, size_t ws_size,
                              hipStream_t stream) {
  const float* x = (const float*)d_in[0];
  const float* Wq = (const float*)d_in[1];
  const float* Wp = (const float*)d_in[2];
  const float* Wk = (const float*)d_in[3];
  const float* Wv = (const float*)d_in[4];
  const float* Wo = (const float*)d_in[5];
  const float* bo = (const float*)d_in[6];
  const float* gamma = (const float*)d_in[7];
  const float* beta = (const float*)d_in[8];
  const float* dt = (const float*)d_in[9];
  const float* gate = (const float*)d_in[10];

  char* ws = (char*)d_ws;
  const size_t szb = (size_t)nM * nD * 2;  // 6,291,456 bytes per bf16 [4096][768]
  bf16* xb = (bf16*)(ws + 0 * szb);        // reused as qn after QPKV GEMM
  bf16* qf = (bf16*)(ws + 1 * szb);
  bf16* pf = (bf16*)(ws + 2 * szb);
  bf16* kf_ = (bf16*)(ws + 3 * szb);
  bf16* vt = (bf16*)(ws + 4 * szb);
  bf16* wt = (bf16*)(ws + 5 * szb);  // 5 * 768*768 bf16 = 5,898,240 bytes
  bf16* qn = xb;
  float* outp = (float*)d_out;  // out-GEMM result, LN runs in place

  k_prep_x<<<dim3(nM * nD / 1024), dim3(256), 0, stream>>>(x, xb);
  k_prep_w<<<dim3(12, 12, 5), dim3(256), 0, stream>>>(Wq, Wp, Wk, Wv, Wo, wt);
  k_gemm_qpkv<<<dim3(6, 32, 4), dim3(256), 0, stream>>>(xb, wt, qf, pf, kf_, vt);
  k_attn<<<dim3(768), dim3(256), 0, stream>>>(qf, pf, kf_, vt, dt, gate, qn);
  k_gemm_out<<<dim3(6, 32), dim3(256), 0, stream>>>(qn, wt + 4 * (size_t)nD * nD, bo, x, outp);
  k_ln<<<dim3(nM / 4), dim3(256), 0, stream>>>(outp, gamma, beta, (float*)d_out);
}